// Round 11
// baseline (235.325 us; speedup 1.0000x reference)
//
#include <hip/hip_runtime.h>
#include <hip/hip_bf16.h>
#include <hip/hip_fp16.h>

typedef _Float16 f16;
typedef _Float16 f16x8 __attribute__((ext_vector_type(8)));
typedef float f32x16 __attribute__((ext_vector_type(16)));
typedef unsigned int u32;

// Problem sizes (fixed)
#define BB 32
#define SS 2048
#define HH 1024
#define KK 1024

// ws layout (bytes)
#define WS_BP 0                            // packed Wv fp16: 2 MB
#define WS_HQ (2u*1024u*1024u)             // hq fp32: 32*1024*4 = 128 KB
#define WS_LP (WS_HQ + 131072u)            // logits partials: 4*32*2048*4 = 1 MB

__device__ __forceinline__ float tanh_f(float x) {
    // tanh(x) = 1 - 2/(e^{2x}+1); safe at +/-inf of exp
    float e = __expf(2.0f * x);
    return 1.0f - 2.0f * __builtin_amdgcn_rcpf(e + 1.0f);
}

// fp32x8 -> fp16x8 cvt + 16B LDS store
__device__ __forceinline__ void write_a16(char* dst, int off, float4 va, float4 vb) {
    union { f16 h[8]; uint4 u; } pk;
    pk.h[0] = (f16)va.x; pk.h[1] = (f16)va.y; pk.h[2] = (f16)va.z; pk.h[3] = (f16)va.w;
    pk.h[4] = (f16)vb.x; pk.h[5] = (f16)vb.y; pk.h[6] = (f16)vb.z; pk.h[7] = (f16)vb.w;
    *(uint4*)(dst + off) = pk.u;
}

// ---------------------------------------------------------------------------
// Pack Wv [k][n] fp32 -> fragment-ordered fp16 for mfma_f32_32x32x16_f16 B.
// Layout: BP[ntb(4)][kit(16)][wc(4)][ks(4)][ntl(2)][lane(64)][j(8)]
//   n = ntb*256 + wc*64 + ntl*32 + (lane&31); k = kit*64 + ks*16 + (lane>>5)*8 + j
// Per (block, wave, epoch): one contiguous 8 KB chunk of 8 x 1KB frags.
__global__ void pack_wv(const float* __restrict__ Wv, f16* __restrict__ BP) {
    int i = blockIdx.x * 256 + threadIdx.x;   // i = k*1024 + n
    int k = i >> 10, n = i & 1023;
    float v = Wv[i];
    int ntb = n >> 8, wc = (n >> 6) & 3, ntl = (n >> 5) & 1, nl = n & 31;
    int kit = k >> 6, ks = (k >> 4) & 3, lg = (k >> 3) & 1, j = k & 7;
    int lane = lg * 32 + nl;
    BP[((((((ntb * 16 + kit) * 4 + wc) * 4 + ks) * 2 + ntl) * 64 + lane) * 8) + j] = (f16)v;
}

// ---------------------------------------------------------------------------
// hq = query @ Wq + bq  (fp32). K split 4 ways, atomicAdd combine.
__global__ void hq_kernel(const float* __restrict__ query, const float* __restrict__ Wq,
                          const float* __restrict__ bq, float* __restrict__ hq) {
    int b = blockIdx.y;
    int h = (blockIdx.x & 3) * 256 + threadIdx.x;
    int v0 = (blockIdx.x >> 2) * 256;
    float acc = 0.f;
#pragma unroll 8
    for (int v = 0; v < 256; ++v)
        acc += query[b * 1024 + v0 + v] * Wq[(v0 + v) * 1024 + h];
    if (v0 == 0) acc += bq[h];
    atomicAdd(&hq[b * 1024 + h], acc);
}

// ---------------------------------------------------------------------------
// Fused 128x256x(K=1024) GEMM tile + tanh(hq+hv)·w row-reduction.
// Round-5 sync skeleton (lgkm(0)+raw barrier per epoch, vmcnt NEVER drained)
// + round-8 B-in-registers (fragment-packed Wv straight L2->VGPR, no B LDS)
// + BK=64 epochs (16 barriers total, 16 MFMA/wave/epoch).
// 8 waves (2wr x 4wc), wave tile 64x64, acc 64 VGPR; LDS = A dbuf 2x16KB only
// -> 2 blocks/CU co-resident (cross-block overlap covers barrier drains).
// A LDS frag-ordered [mtb(4)][ks(4)][lane(64)][j(8)]: conflict-free reads.
__launch_bounds__(512, 4)
__global__ void fused_main(const float* __restrict__ value, const f16* __restrict__ BP,
                           const float* __restrict__ hq, const float* __restrict__ wvec,
                           float* __restrict__ lpart) {
    extern __shared__ char smem[];             // 32 KB: A0 [0,16K), A1 [16K,32K)

    int bid = blockIdx.x;
    int tile = (bid & 7) * 256 + (bid >> 3);   // XCD swizzle; 4 ntb of one Mt co-XCD
    int Mt = tile >> 2, ntb = tile & 3;
    int m0 = Mt << 7;                          // 128 rows
    int b = m0 >> 11, s0 = m0 & 2047;

    int tid = threadIdx.x;
    int w = tid >> 6, l = tid & 63;
    int wr = w >> 2, wc = w & 3;
    int l31 = l & 31, lg = l >> 5;

    // ---- A staging: thread t covers row tid>>2 (0..127), 16 floats at (tid&3)*16
    int arow = tid >> 2;
    const float* aga = value + (size_t)(m0 + arow) * 1024 + (tid & 3) * 16;
    // frag slot: row covers one ks = tid&3; two 8-elem j-groups (lg8 = 0,1)
    int aw0 = ((arow >> 5) * 4 + (tid & 3)) * 1024 + ((arow & 31) << 4);
    int aw1 = aw0 + 512;                       // lg8=1: lane += 32 -> +32*16B

    // ---- B per-wave global base (epoch chunk = 8 KB; frag f = ks*2+ntl at f*1024)
    const char* bg = (const char*)BP + (size_t)ntb * 524288 + (size_t)wc * 8192
                   + (size_t)l * 16;

    // ---- A frag read offsets (conflict-free lane*16), + ks*1024 per slice
    int a_off0 = (wr * 2 + 0) * 4096 + l * 16;
    int a_off1 = (wr * 2 + 1) * 4096 + l * 16;

    const f32x16 fzero = {};
    f32x16 acc[2][2];
#pragma unroll
    for (int mt = 0; mt < 2; ++mt)
#pragma unroll
        for (int nt = 0; nt < 2; ++nt) acc[mt][nt] = fzero;

    float4 ar0, ar1, ar2, ar3;                 // next-tile A (1-epoch cover)

    // ---- prologue: A tile 0 -> LDS A0
    {
        const float4* ap = (const float4*)aga;
        float4 p0 = ap[0], p1 = ap[1], p2 = ap[2], p3 = ap[3];
        write_a16(smem, aw0, p0, p1);
        write_a16(smem, aw1, p2, p3);
        asm volatile("s_waitcnt lgkmcnt(0)" ::: "memory");
        __builtin_amdgcn_s_barrier();
    }

    // ---- main loop: 16 epochs of BK=64; barriers carry NO vmcnt
#pragma unroll 1
    for (int t = 0; t < 16; ++t) {
        const char* Ac = smem + (t & 1) * 16384;
        char* An = smem + ((t + 1) & 1) * 16384;
        const char* bt = bg + (size_t)t * 32768;

        if (t < 15) {                          // issue A(t+1): full-epoch cover
            const float4* ap = (const float4*)(aga + (t + 1) * 64);
            ar0 = ap[0]; ar1 = ap[1]; ar2 = ap[2]; ar3 = ap[3];
        }

        // compute: 2 k-halves x (4 B L2->reg loads + 4 A ds_reads + 8 MFMA)
#pragma unroll
        for (int h = 0; h < 2; ++h) {
            f16x8 bv00 = *(const f16x8*)(bt + ((2 * h + 0) * 2 + 0) * 1024);
            f16x8 bv01 = *(const f16x8*)(bt + ((2 * h + 0) * 2 + 1) * 1024);
            f16x8 bv10 = *(const f16x8*)(bt + ((2 * h + 1) * 2 + 0) * 1024);
            f16x8 bv11 = *(const f16x8*)(bt + ((2 * h + 1) * 2 + 1) * 1024);
            f16x8 a00 = *(const f16x8*)(Ac + a_off0 + (2 * h + 0) * 1024);
            f16x8 a10 = *(const f16x8*)(Ac + a_off1 + (2 * h + 0) * 1024);
            f16x8 a01 = *(const f16x8*)(Ac + a_off0 + (2 * h + 1) * 1024);
            f16x8 a11 = *(const f16x8*)(Ac + a_off1 + (2 * h + 1) * 1024);
            __builtin_amdgcn_s_setprio(1);
            acc[0][0] = __builtin_amdgcn_mfma_f32_32x32x16_f16(a00, bv00, acc[0][0], 0, 0, 0);
            acc[0][1] = __builtin_amdgcn_mfma_f32_32x32x16_f16(a00, bv01, acc[0][1], 0, 0, 0);
            acc[1][0] = __builtin_amdgcn_mfma_f32_32x32x16_f16(a10, bv00, acc[1][0], 0, 0, 0);
            acc[1][1] = __builtin_amdgcn_mfma_f32_32x32x16_f16(a10, bv01, acc[1][1], 0, 0, 0);
            acc[0][0] = __builtin_amdgcn_mfma_f32_32x32x16_f16(a01, bv10, acc[0][0], 0, 0, 0);
            acc[0][1] = __builtin_amdgcn_mfma_f32_32x32x16_f16(a01, bv11, acc[0][1], 0, 0, 0);
            acc[1][0] = __builtin_amdgcn_mfma_f32_32x32x16_f16(a11, bv10, acc[1][0], 0, 0, 0);
            acc[1][1] = __builtin_amdgcn_mfma_f32_32x32x16_f16(a11, bv11, acc[1][1], 0, 0, 0);
            __builtin_amdgcn_s_setprio(0);
        }

        if (t < 15) {                          // cvt + write A(t+1) to other buffer
            write_a16(An, aw0, ar0, ar1);
            write_a16(An, aw1, ar2, ar3);
        }
        asm volatile("s_waitcnt lgkmcnt(0)" ::: "memory");
        __builtin_amdgcn_s_barrier();
    }

    // ---- epilogue: t = tanh(hq + hv) * w, pair-folded col reduction
    int h0 = ntb * 256 + wc * 64 + l31;   // nt = 0
    int h1 = h0 + 32;                     // nt = 1
    float hq0 = hq[b * 1024 + h0], hq1 = hq[b * 1024 + h1];
    float w0 = wvec[h0], w1 = wvec[h1];

    float* part = (float*)smem;           // 2 KB [wc(4)][row(128)]; A dead now
#pragma unroll
    for (int mt = 0; mt < 2; ++mt) {
#pragma unroll
        for (int i = 0; i < 8; ++i) {
            float pa = tanh_f(hq0 + acc[mt][0][2 * i]) * w0
                     + tanh_f(hq1 + acc[mt][1][2 * i]) * w1;
            float pb = tanh_f(hq0 + acc[mt][0][2 * i + 1]) * w0
                     + tanh_f(hq1 + acc[mt][1][2 * i + 1]) * w1;
            float ea = __shfl_xor(pa, 1), eb = __shfl_xor(pb, 1);
            float g = (l & 1) ? (pb + eb) : (pa + ea);
            g += __shfl_xor(g, 2); g += __shfl_xor(g, 4);
            g += __shfl_xor(g, 8); g += __shfl_xor(g, 16);
            if (l31 < 2) {
                int r = 2 * i + (l31 & 1);
                int row = wr * 64 + mt * 32 + (r & 3) + ((r >> 2) << 3) + (lg << 2);
                part[wc * 128 + row] = g;
            }
        }
    }
    __syncthreads();
    if (tid < 128) {
        float s = part[tid] + part[128 + tid] + part[256 + tid] + part[384 + tid];
        lpart[((size_t)ntb * 32 + b) * 2048 + s0 + tid] = s;
    }
}

// ---------------------------------------------------------------------------
// Masked softmax over S=2048 per b, summing the 4 N-block logit partials.
__global__ void softmax_kernel(const float* __restrict__ lp, const int* __restrict__ mask,
                               float* __restrict__ out) {
    __shared__ float redm[16];
    __shared__ float reds[16];
    const int P = 32 * 2048;
    int b = blockIdx.x, t = threadIdx.x;
    int wid = t >> 6, lane = t & 63;
    int i0 = b * 2048 + t, i1 = i0 + 1024;
    float l0 = lp[i0] + lp[P + i0] + lp[2 * P + i0] + lp[3 * P + i0];
    float l1 = lp[i1] + lp[P + i1] + lp[2 * P + i1] + lp[3 * P + i1];
    float a0 = mask[i0] ? l0 : -1e9f;
    float a1 = mask[i1] ? l1 : -1e9f;
    float mx = fmaxf(a0, a1);
#pragma unroll
    for (int off = 1; off < 64; off <<= 1) mx = fmaxf(mx, __shfl_xor(mx, off));
    if (lane == 0) redm[wid] = mx;
    __syncthreads();
    mx = redm[0];
#pragma unroll
    for (int i = 1; i < 16; ++i) mx = fmaxf(mx, redm[i]);
    float e0 = __expf(a0 - mx), e1 = __expf(a1 - mx);
    float s = e0 + e1;
#pragma unroll
    for (int off = 1; off < 64; off <<= 1) s += __shfl_xor(s, off);
    if (lane == 0) reds[wid] = s;
    __syncthreads();
    float tot = 0.f;
#pragma unroll
    for (int i = 0; i < 16; ++i) tot += reds[i];
    float inv = 1.0f / tot;
    out[b * 2048 + t] = e0 * inv;
    out[b * 2048 + 1024 + t] = e1 * inv;
}

// ---------------------------------------------------------------------------
extern "C" void kernel_launch(void* const* d_in, const int* in_sizes, int n_in,
                              void* d_out, int out_size, void* d_ws, size_t ws_size,
                              hipStream_t stream) {
    const float* query = (const float*)d_in[0];
    const float* value = (const float*)d_in[1];
    const int*   mask  = (const int*)d_in[2];
    const float* Wq    = (const float*)d_in[3];
    const float* bq    = (const float*)d_in[4];
    const float* Wv    = (const float*)d_in[5];
    const float* wv    = (const float*)d_in[6];

    char* ws = (char*)d_ws;
    f16*   BP    = (f16*)(ws + WS_BP);
    float* hq    = (float*)(ws + WS_HQ);
    float* lpart = (float*)(ws + WS_LP);
    float* out   = (float*)d_out;

    (void)hipMemsetAsync(hq, 0, BB * HH * sizeof(float), stream);
    pack_wv<<<(KK * HH) / 256, 256, 0, stream>>>(Wv, BP);
    hq_kernel<<<dim3(16, BB), 256, 0, stream>>>(query, Wq, bq, hq);
    fused_main<<<2048, 512, 32768, stream>>>(value, BP, hq, wv, lpart);
    softmax_kernel<<<BB, 1024, 0, stream>>>(lpart, mask, out);
}